// Round 3
// baseline (621.662 us; speedup 1.0000x reference)
//
#include <hip/hip_runtime.h>

// Fused MS-SSIM + L1, single pass. B=128, H=W=384 fp32.
// Levels k=1,2,4,7, box conv, zero pad p=k/2 (even k -> 385x385 output).
// Per wave: 64 lanes = 64 window-start columns (stride 56, halo 8).
// Each lane loads its own overlapped 7-elem row window from global (no LDS,
// no cross-lane) -> horizontal sums are local adds. Vertical sums via
// register ring buffers, row loop unrolled by 6 = LCM(1,3,6) so ring
// shifts are register-renamed. SSIM in unnormalized (k^4-scaled) form.

#define W 384
#define H 384
#define NB 128
#define BAND 49
#define NBANDS 8
#define NTILES 7

__global__ void zero_acc_kernel(double* acc) {
    if (threadIdx.x < 5) acc[threadIdx.x] = 0.0;
}

// S for box window of k*k using UNNORMALIZED sums V = {Sx,Sy,Sxx,Syy,Sxy}.
// k2 = k^2, c1k4 = C1*k^4, c2k4 = C2*k^4. (1/k^2 factors cancel.)
__device__ __forceinline__ float ssim_u(const float* V, float k2, float c1k4, float c2k4) {
    const float Sx = V[0], Sy = V[1], Sxx = V[2], Syy = V[3], Sxy = V[4];
    const float p  = Sx * Sy;
    float sq = Sx * Sx;
    sq = fmaf(Sy, Sy, sq);
    const float A1 = fmaf(2.f, p, c1k4);
    const float t  = fmaf(k2, Sxy, -p);
    const float A2 = fmaf(2.f, t, c2k4);
    const float B1 = sq + c1k4;
    const float sw = Sxx + Syy;
    const float B2 = fmaf(k2, sw, -sq) + c2k4;
    return (A1 * A2) * __builtin_amdgcn_rcpf(B1 * B2);
}

__global__ __launch_bounds__(256, 2) void msssim_fused_kernel(
    const float* __restrict__ X, const float* __restrict__ Y,
    const float* __restrict__ dr, double* __restrict__ acc)
{
    const int lane = threadIdx.x & 63;
    const int wv   = threadIdx.x >> 6;        // 0..3
    const int tile = blockIdx.x * 4 + wv;     // 0..7 (7 idle)
    const int band = blockIdx.y;
    const int b    = blockIdx.z;
    if (tile >= NTILES) return;

    const int cbase = -3 + 56 * tile;   // window-start col of lane 0
    const int c     = cbase + lane;
    const int R0    = BAND * band;
    const int R1    = R0 + BAND;

    const float drb = dr[b];
    const float C1 = (0.01f * drb) * (0.01f * drb);
    const float C2 = (0.03f * drb) * (0.03f * drb);
    const float C1_2 = C1 * 16.f,   C2_2 = C2 * 16.f;     // k=2, k^4=16
    const float C1_4 = C1 * 256.f,  C2_4 = C2 * 256.f;    // k=4, 256
    const float C1_7 = C1 * 2401.f, C2_7 = C2 * 2401.f;   // k=7, 2401

    // ownership masks (validated in round 2): j = c + k/2
    const float m1 = (lane >= 3 && lane <= 58 && c     <= 383) ? 1.f : 0.f;
    const float m2 = (lane >= 2 && lane <= 57 && c + 1 <= 384) ? 1.f : 0.f;
    const float m4 = (lane >= 1 && lane <= 56 && c + 2 <= 384) ? 1.f : 0.f;
    const float m7 = (             lane <= 55 && c + 3 <= 383) ? 1.f : 0.f;

    // clamped column offsets + validity masks (row-invariant)
    int   cci[7];
    float mc[7];
#pragma unroll
    for (int i = 0; i < 7; ++i) {
        const int col = c + i;
        mc[i]  = (col >= 0 && col < W) ? 1.f : 0.f;
        cci[i] = col < 0 ? 0 : (col > W - 1 ? W - 1 : col);
    }

    const float* __restrict__ Xb = X + (size_t)b * (H * W);
    const float* __restrict__ Yb = Y + (size_t)b * (H * W);

    auto load_row = [&](int u, float* xr, float* yr) {
        if (u >= 0 && u < H) {
            const float* __restrict__ rx = Xb + (size_t)u * W;
            const float* __restrict__ ry = Yb + (size_t)u * W;
#pragma unroll
            for (int i = 0; i < 7; ++i) {
                xr[i] = rx[cci[i]] * mc[i];
                yr[i] = ry[cci[i]] * mc[i];
            }
        } else {
#pragma unroll
            for (int i = 0; i < 7; ++i) { xr[i] = 0.f; yr[i] = 0.f; }
        }
    };

    // vertical ring buffers of horizontal window sums (per quantity)
    float r2[5], r4[3][5], r7[6][5];
#pragma unroll
    for (int q = 0; q < 5; ++q) {
        r2[q] = 0.f;
        r4[0][q] = r4[1][q] = r4[2][q] = 0.f;
#pragma unroll
        for (int a = 0; a < 6; ++a) r7[a][q] = 0.f;
    }

    float ss1 = 0.f, ss2 = 0.f, ss4 = 0.f, ss7 = 0.f, l1 = 0.f;

    const int u0    = R0 - 3;
    const int u_end = (R1 + 2 < 386) ? (R1 + 2) : 386;

    float xc[7], yc[7];
    load_row(u0, xc, yc);

    for (int base = u0; base <= u_end; base += 6) {
#pragma unroll
        for (int ph = 0; ph < 6; ++ph) {
            const int u = base + ph;
            if (u > u_end) break;

            // prefetch next row (consumed next phase)
            float xn[7], yn[7];
            load_row(u + 1, xn, yn);

            float V2[5], V4[5], V7[5];
#pragma unroll
            for (int q = 0; q < 5; ++q) {
                float e[7];
#pragma unroll
                for (int i = 0; i < 7; ++i) {
                    e[i] = (q == 0) ? xc[i]
                         : (q == 1) ? yc[i]
                         : (q == 2) ? xc[i] * xc[i]
                         : (q == 3) ? yc[i] * yc[i]
                         :            xc[i] * yc[i];
                }
                const float w2 = e[0] + e[1];
                const float w4 = w2 + (e[2] + e[3]);
                const float w7 = w4 + ((e[4] + e[5]) + e[6]);
                V2[q] = w2 + r2[q];
                V4[q] = w4 + (r4[0][q] + r4[1][q] + r4[2][q]);
                V7[q] = w7 + ((r7[0][q] + r7[1][q]) + (r7[2][q] + r7[3][q])
                              + (r7[4][q] + r7[5][q]));
                r2[q] = w2;
                r4[2][q] = r4[1][q]; r4[1][q] = r4[0][q]; r4[0][q] = w4;
                r7[5][q] = r7[4][q]; r7[4][q] = r7[3][q]; r7[3][q] = r7[2][q];
                r7[2][q] = r7[1][q]; r7[1][q] = r7[0][q]; r7[0][q] = w7;
            }

            // k=1 (closed form), output row i=u
            if (u >= R0 && u < R1 && u < 384) {
                const float xx0 = xc[0] * xc[0];
                const float yy0 = yc[0] * yc[0];
                const float xy0 = xc[0] * yc[0];
                const float s = fmaf(2.f, xy0, C1) *
                                __builtin_amdgcn_rcpf(xx0 + yy0 + C1);
                ss1 = fmaf(s, m1, ss1);
            }
            // k=2, i=u
            if (u >= R0 && u < R1 && u < 385) {
                ss2 = fmaf(ssim_u(V2, 4.f, C1_2, C2_2), m2, ss2);
            }
            // k=4, i=u-1
            {
                const int i = u - 1;
                if (i >= R0 && i < R1 && i < 385) {
                    ss4 = fmaf(ssim_u(V4, 16.f, C1_4, C2_4), m4, ss4);
                }
            }
            // k=7, i=u-3, plus L1 (|Sx-Sy|, 1/49 applied in finalize)
            {
                const int i = u - 3;
                if (i >= R0 && i < R1 && i < 384) {
                    ss7 = fmaf(ssim_u(V7, 49.f, C1_7, C2_7), m7, ss7);
                    l1  = fmaf(fabsf(V7[0] - V7[1]), m7, l1);
                }
            }

#pragma unroll
            for (int i = 0; i < 7; ++i) { xc[i] = xn[i]; yc[i] = yn[i]; }
        }
    }

    // wave reduction
#pragma unroll
    for (int d = 32; d > 0; d >>= 1) {
        ss1 += __shfl_down(ss1, d, 64);
        ss2 += __shfl_down(ss2, d, 64);
        ss4 += __shfl_down(ss4, d, 64);
        ss7 += __shfl_down(ss7, d, 64);
        l1  += __shfl_down(l1,  d, 64);
    }
    if (lane == 0) {
        atomicAdd(&acc[0], (double)ss1);
        atomicAdd(&acc[1], (double)ss2);
        atomicAdd(&acc[2], (double)ss4);
        atomicAdd(&acc[3], (double)ss7);
        atomicAdd(&acc[4], (double)l1);
    }
}

__global__ void finalize_kernel(const double* __restrict__ acc, float* __restrict__ out) {
    const double n384 = (double)NB * 384.0 * 384.0;
    const double n385 = (double)NB * 385.0 * 385.0;
    const double m  = (acc[0] / n384) * (acc[1] / n385) * (acc[2] / n385) * (acc[3] / n384);
    const double l1 = acc[4] / 49.0 / n384;
    out[0] = (float)(0.84 * (1.0 - m) + 0.16 * l1);
}

extern "C" void kernel_launch(void* const* d_in, const int* in_sizes, int n_in,
                              void* d_out, int out_size, void* d_ws, size_t ws_size,
                              hipStream_t stream) {
    const float* X  = (const float*)d_in[0];
    const float* Y  = (const float*)d_in[1];
    const float* dr = (const float*)d_in[2];
    float* out  = (float*)d_out;
    double* acc = (double*)d_ws;

    zero_acc_kernel<<<1, 64, 0, stream>>>(acc);

    dim3 grid(2, NBANDS, NB);   // 2 strip-groups x 4 waves = 8 strips (7 live)
    msssim_fused_kernel<<<grid, 256, 0, stream>>>(X, Y, dr, acc);

    finalize_kernel<<<1, 1, 0, stream>>>(acc, out);
}

// Round 4
// 415.571 us; speedup vs baseline: 1.4959x; 1.4959x over previous
//
#include <hip/hip_runtime.h>

// Fused MS-SSIM + L1, single pass. B=128, H=W=384 fp32.
// Levels k=1,2,4,7, box conv, zero pad p=k/2 (even k -> 385x385 output).
// Per wave: 64 lanes = 64 window-start columns (stride 56, halo 8).
// Each lane loads its own overlapped 7-elem row window (coalesced per
// shift-offset across lanes). Horizontal sums local; vertical sums via
// register ring buffers; row loop unrolled by 6 = LCM(1,3,6).
// Round 4: prefetch depth 2 (3-slot rotating register row buffer),
// no atomics (per-block partials + tiny reduce kernel), zero idle waves.

#define W 384
#define H 384
#define NB 128
#define BAND 49
#define NTILES 7
#define NBLK (NTILES * 2 * NB)   // grid (7,2,128) = 1792 blocks

// S for box window k*k from UNNORMALIZED sums V = {Sx,Sy,Sxx,Syy,Sxy}.
// k2 = k^2, c1k4 = C1*k^4, c2k4 = C2*k^4 (1/k^2 factors cancel).
__device__ __forceinline__ float ssim_u(const float* V, float k2, float c1k4, float c2k4) {
    const float Sx = V[0], Sy = V[1], Sxx = V[2], Syy = V[3], Sxy = V[4];
    const float p  = Sx * Sy;
    float sq = Sx * Sx;
    sq = fmaf(Sy, Sy, sq);
    const float A1 = fmaf(2.f, p, c1k4);
    const float t  = fmaf(k2, Sxy, -p);
    const float A2 = fmaf(2.f, t, c2k4);
    const float B1 = sq + c1k4;
    const float sw = Sxx + Syy;
    const float B2 = fmaf(k2, sw, -sq) + c2k4;
    return (A1 * A2) * __builtin_amdgcn_rcpf(B1 * B2);
}

__global__ __launch_bounds__(256) void msssim_main(
    const float* __restrict__ X, const float* __restrict__ Y,
    const float* __restrict__ dr, float* __restrict__ part)
{
    const int lane = threadIdx.x & 63;
    const int wv   = threadIdx.x >> 6;          // 0..3
    const int tile = blockIdx.x;                // 0..6
    const int band = blockIdx.y * 4 + wv;       // 0..7
    const int b    = blockIdx.z;

    const int cbase = -3 + 56 * tile;           // window-start col of lane 0
    const int c     = cbase + lane;
    const int R0    = BAND * band;
    const int R1    = R0 + BAND;

    const float drb = dr[b];
    const float C1 = (0.01f * drb) * (0.01f * drb);
    const float C2 = (0.03f * drb) * (0.03f * drb);
    const float C1_2 = C1 * 16.f,   C2_2 = C2 * 16.f;     // k=2
    const float C1_4 = C1 * 256.f,  C2_4 = C2 * 256.f;    // k=4
    const float C1_7 = C1 * 2401.f, C2_7 = C2 * 2401.f;   // k=7

    // ownership masks (validated rounds 2-3): output col j = c + k/2
    const float m1 = (lane >= 3 && lane <= 58 && c     <= 383) ? 1.f : 0.f;
    const float m2 = (lane >= 2 && lane <= 57 && c + 1 <= 384) ? 1.f : 0.f;
    const float m4 = (lane >= 1 && lane <= 56 && c + 2 <= 384) ? 1.f : 0.f;
    const float m7 = (             lane <= 55 && c + 3 <= 383) ? 1.f : 0.f;

    // clamped column offsets + validity masks (row-invariant)
    int   cci[7];
    float mc[7];
#pragma unroll
    for (int i = 0; i < 7; ++i) {
        const int col = c + i;
        mc[i]  = (col >= 0 && col < W) ? 1.f : 0.f;
        cci[i] = col < 0 ? 0 : (col > W - 1 ? W - 1 : col);
    }

    const float* __restrict__ Xb = X + (size_t)b * (H * W);
    const float* __restrict__ Yb = Y + (size_t)b * (H * W);

    // 3-slot rotating row buffer: [slot][0..6]=x window, [slot][7..13]=y window
    float buf[3][14];
    auto load_row = [&](int u, float* d) {
        if (u >= 0 && u < H) {
            const float* __restrict__ rx = Xb + (size_t)u * W;
            const float* __restrict__ ry = Yb + (size_t)u * W;
#pragma unroll
            for (int i = 0; i < 7; ++i) {
                d[i]     = rx[cci[i]] * mc[i];
                d[7 + i] = ry[cci[i]] * mc[i];
            }
        } else {
#pragma unroll
            for (int i = 0; i < 14; ++i) d[i] = 0.f;
        }
    };

    // vertical ring buffers of horizontal window sums (per quantity)
    float r2[5], r4[3][5], r7[6][5];
#pragma unroll
    for (int q = 0; q < 5; ++q) {
        r2[q] = 0.f;
        r4[0][q] = r4[1][q] = r4[2][q] = 0.f;
#pragma unroll
        for (int a = 0; a < 6; ++a) r7[a][q] = 0.f;
    }

    float ss1 = 0.f, ss2 = 0.f, ss4 = 0.f, ss7 = 0.f, l1 = 0.f;

    const int u0    = R0 - 3;
    const int u_end = (R1 + 2 < 386) ? (R1 + 2) : 386;

    load_row(u0,     buf[0]);
    load_row(u0 + 1, buf[1]);

    for (int base = u0; base <= u_end; base += 6) {
#pragma unroll
        for (int ph = 0; ph < 6; ++ph) {
            const int u = base + ph;
            if (u > u_end) break;

            // prefetch row u+2 into the slot freed two phases ago
            load_row(u + 2, buf[(ph + 2) % 3]);

            const float* xc = buf[ph % 3];
            const float* yc = buf[ph % 3] + 7;

            float V2[5], V4[5], V7[5];
#pragma unroll
            for (int q = 0; q < 5; ++q) {
                float e[7];
#pragma unroll
                for (int i = 0; i < 7; ++i) {
                    e[i] = (q == 0) ? xc[i]
                         : (q == 1) ? yc[i]
                         : (q == 2) ? xc[i] * xc[i]
                         : (q == 3) ? yc[i] * yc[i]
                         :            xc[i] * yc[i];
                }
                const float w2 = e[0] + e[1];
                const float w4 = w2 + (e[2] + e[3]);
                const float w7 = w4 + ((e[4] + e[5]) + e[6]);
                V2[q] = w2 + r2[q];
                V4[q] = w4 + (r4[0][q] + r4[1][q] + r4[2][q]);
                V7[q] = w7 + ((r7[0][q] + r7[1][q]) + (r7[2][q] + r7[3][q])
                              + (r7[4][q] + r7[5][q]));
                r2[q] = w2;
                r4[2][q] = r4[1][q]; r4[1][q] = r4[0][q]; r4[0][q] = w4;
                r7[5][q] = r7[4][q]; r7[4][q] = r7[3][q]; r7[3][q] = r7[2][q];
                r7[2][q] = r7[1][q]; r7[1][q] = r7[0][q]; r7[0][q] = w7;
            }

            // k=1 (closed form), output row i=u
            if (u >= R0 && u < R1 && u < 384) {
                const float xx0 = xc[0] * xc[0];
                const float yy0 = yc[0] * yc[0];
                const float xy0 = xc[0] * yc[0];
                const float s = fmaf(2.f, xy0, C1) *
                                __builtin_amdgcn_rcpf(xx0 + yy0 + C1);
                ss1 = fmaf(s, m1, ss1);
            }
            // k=2, i=u
            if (u >= R0 && u < R1 && u < 385) {
                ss2 = fmaf(ssim_u(V2, 4.f, C1_2, C2_2), m2, ss2);
            }
            // k=4, i=u-1
            {
                const int i = u - 1;
                if (i >= R0 && i < R1 && i < 385) {
                    ss4 = fmaf(ssim_u(V4, 16.f, C1_4, C2_4), m4, ss4);
                }
            }
            // k=7, i=u-3, plus L1 (|Sx-Sy|, 1/49 applied in reduce)
            {
                const int i = u - 3;
                if (i >= R0 && i < R1 && i < 384) {
                    ss7 = fmaf(ssim_u(V7, 49.f, C1_7, C2_7), m7, ss7);
                    l1  = fmaf(fabsf(V7[0] - V7[1]), m7, l1);
                }
            }
        }
    }

    // wave reduce -> block reduce -> one float store per block per quantity
#pragma unroll
    for (int d = 32; d > 0; d >>= 1) {
        ss1 += __shfl_down(ss1, d, 64);
        ss2 += __shfl_down(ss2, d, 64);
        ss4 += __shfl_down(ss4, d, 64);
        ss7 += __shfl_down(ss7, d, 64);
        l1  += __shfl_down(l1,  d, 64);
    }
    __shared__ float sred[4][5];
    if (lane == 0) {
        sred[wv][0] = ss1; sred[wv][1] = ss2; sred[wv][2] = ss4;
        sred[wv][3] = ss7; sred[wv][4] = l1;
    }
    __syncthreads();
    if (threadIdx.x == 0) {
        const int bid = ((int)blockIdx.z * 2 + (int)blockIdx.y) * NTILES + (int)blockIdx.x;
#pragma unroll
        for (int q = 0; q < 5; ++q)
            part[bid * 5 + q] = sred[0][q] + sred[1][q] + sred[2][q] + sred[3][q];
    }
}

__global__ __launch_bounds__(256) void reduce_final(
    const float* __restrict__ part, float* __restrict__ out)
{
    const int lane = threadIdx.x & 63;
    const int wv   = threadIdx.x >> 6;
    double d[5] = {0, 0, 0, 0, 0};
    for (int i = threadIdx.x; i < NBLK; i += 256) {
#pragma unroll
        for (int q = 0; q < 5; ++q) d[q] += (double)part[i * 5 + q];
    }
#pragma unroll
    for (int s = 32; s > 0; s >>= 1) {
#pragma unroll
        for (int q = 0; q < 5; ++q) d[q] += __shfl_down(d[q], s, 64);
    }
    __shared__ double sd[4][5];
    if (lane == 0) {
#pragma unroll
        for (int q = 0; q < 5; ++q) sd[wv][q] = d[q];
    }
    __syncthreads();
    if (threadIdx.x == 0) {
        double a[5];
#pragma unroll
        for (int q = 0; q < 5; ++q)
            a[q] = sd[0][q] + sd[1][q] + sd[2][q] + sd[3][q];
        const double n384 = (double)NB * 384.0 * 384.0;
        const double n385 = (double)NB * 385.0 * 385.0;
        const double m  = (a[0] / n384) * (a[1] / n385) * (a[2] / n385) * (a[3] / n384);
        const double l1 = a[4] / 49.0 / n384;
        out[0] = (float)(0.84 * (1.0 - m) + 0.16 * l1);
    }
}

extern "C" void kernel_launch(void* const* d_in, const int* in_sizes, int n_in,
                              void* d_out, int out_size, void* d_ws, size_t ws_size,
                              hipStream_t stream) {
    const float* X  = (const float*)d_in[0];
    const float* Y  = (const float*)d_in[1];
    const float* dr = (const float*)d_in[2];
    float* out  = (float*)d_out;
    float* part = (float*)d_ws;   // NBLK*5 floats = 35.8 KB

    dim3 grid(NTILES, 2, NB);
    msssim_main<<<grid, 256, 0, stream>>>(X, Y, dr, part);
    reduce_final<<<1, 256, 0, stream>>>(part, out);
}

// Round 5
// 309.087 us; speedup vs baseline: 2.0113x; 1.3445x over previous
//
#include <hip/hip_runtime.h>

// Fused MS-SSIM + L1, single pass. B=128, H=W=384 fp32.
// Levels k=1,2,4,7, box conv, zero pad p=k/2 (even k -> 385x385 output).
// Round 5: column ownership. Each lane owns ONE column (window-start col
// c = -3+56*tile+lane), loads 2 values/row (coalesced, SGPR row base +
// fixed voffset). Horizontal neighbors via 12 ds_bpermute shifts/row
// (semantics+masks validated in round 2). Products + hierarchical
// horizontal sums local; vertical via register rings (validated);
// 6-phase unroll; depth-2 prefetch in 3-slot ring; block partials,
// no atomics (validated round 4).

#define W 384
#define H 384
#define NB 128
#define BAND 49
#define NTILES 7
#define NBLK (NTILES * 2 * NB)   // grid (7,2,128) = 1792 blocks

__device__ __forceinline__ float bp(int addr, float v) {
    return __int_as_float(__builtin_amdgcn_ds_bpermute(addr, __float_as_int(v)));
}

// S for box window k*k from UNNORMALIZED sums V = {Sx,Sy,Sxx,Syy,Sxy}.
// k2 = k^2, c1k4 = C1*k^4, c2k4 = C2*k^4 (1/k^2 factors cancel).
__device__ __forceinline__ float ssim_u(const float* V, float k2, float c1k4, float c2k4) {
    const float Sx = V[0], Sy = V[1], Sxx = V[2], Syy = V[3], Sxy = V[4];
    const float p  = Sx * Sy;
    float sq = Sx * Sx;
    sq = fmaf(Sy, Sy, sq);
    const float A1 = fmaf(2.f, p, c1k4);
    const float t  = fmaf(k2, Sxy, -p);
    const float A2 = fmaf(2.f, t, c2k4);
    const float B1 = sq + c1k4;
    const float sw = Sxx + Syy;
    const float B2 = fmaf(k2, sw, -sq) + c2k4;
    return (A1 * A2) * __builtin_amdgcn_rcpf(B1 * B2);
}

__global__ __launch_bounds__(256) void msssim_main(
    const float* __restrict__ X, const float* __restrict__ Y,
    const float* __restrict__ dr, float* __restrict__ part)
{
    const int lane = threadIdx.x & 63;
    const int wv   = threadIdx.x >> 6;          // 0..3
    const int tile = blockIdx.x;                // 0..6
    const int band = blockIdx.y * 4 + wv;       // 0..7
    const int b    = blockIdx.z;

    const int cbase = -3 + 56 * tile;           // window-start col of lane 0
    const int c     = cbase + lane;             // this lane's column
    const int R0    = BAND * band;
    const int R1    = R0 + BAND;

    const float drb = dr[b];
    const float C1 = (0.01f * drb) * (0.01f * drb);
    const float C2 = (0.03f * drb) * (0.03f * drb);
    const float C1_2 = C1 * 16.f,   C2_2 = C2 * 16.f;     // k=2
    const float C1_4 = C1 * 256.f,  C2_4 = C2 * 256.f;    // k=4
    const float C1_7 = C1 * 2401.f, C2_7 = C2 * 2401.f;   // k=7

    // ownership masks (validated rounds 2-4): output col j = c + k/2
    const float m1 = (lane >= 3 && lane <= 58 && c     <= 383) ? 1.f : 0.f;
    const float m2 = (lane >= 2 && lane <= 57 && c + 1 <= 384) ? 1.f : 0.f;
    const float m4 = (lane >= 1 && lane <= 56 && c + 2 <= 384) ? 1.f : 0.f;
    const float m7 = (             lane <= 55 && c + 3 <= 383) ? 1.f : 0.f;

    // own-column load setup (clamped offset + zero mask, row-invariant)
    const float mcol = (c >= 0 && c < W) ? 1.f : 0.f;
    const int   cc   = c < 0 ? 0 : (c > W - 1 ? W - 1 : c);

    // bpermute byte addresses for shifts d=1..6 (hw wraps mod 64; wrapped
    // lanes produce garbage that the ownership masks exclude)
    int ad[6];
#pragma unroll
    for (int d = 1; d <= 6; ++d) ad[d - 1] = ((lane + d) & 63) << 2;

    const float* __restrict__ Xb = X + (size_t)b * (H * W);
    const float* __restrict__ Yb = Y + (size_t)b * (H * W);

    // vertical ring buffers of horizontal window sums (per quantity)
    float r2[5], r4[3][5], r7[6][5];
#pragma unroll
    for (int q = 0; q < 5; ++q) {
        r2[q] = 0.f;
        r4[0][q] = r4[1][q] = r4[2][q] = 0.f;
#pragma unroll
        for (int a = 0; a < 6; ++a) r7[a][q] = 0.f;
    }

    float ss1 = 0.f, ss2 = 0.f, ss4 = 0.f, ss7 = 0.f, l1 = 0.f;

    const int u0    = R0 - 3;
    const int u_end = (R1 + 2 < 386) ? (R1 + 2) : 386;

    // 3-slot rotating prefetch of own-column (x,y); depth 2
    float px[3], py[3];
    auto loadv = [&](int u, float& x, float& y) {
        if (u >= 0 && u < H) {               // wave-uniform branch
            x = Xb[(size_t)u * W + cc] * mcol;
            y = Yb[(size_t)u * W + cc] * mcol;
        } else { x = 0.f; y = 0.f; }
    };
    loadv(u0,     px[0], py[0]);
    loadv(u0 + 1, px[1], py[1]);

    for (int base = u0; base <= u_end; base += 6) {
#pragma unroll
        for (int ph = 0; ph < 6; ++ph) {
            const int u = base + ph;
            if (u > u_end) break;

            loadv(u + 2, px[(ph + 2) % 3], py[(ph + 2) % 3]);

            const float xv = px[ph % 3];
            const float yv = py[ph % 3];

            // shifted raw values (lane i gets column c+d)
            float xa[7], ya[7];
            xa[0] = xv; ya[0] = yv;
#pragma unroll
            for (int d = 1; d <= 6; ++d) {
                xa[d] = bp(ad[d - 1], xv);
                ya[d] = bp(ad[d - 1], yv);
            }

            float V2[5], V4[5], V7[5];
#pragma unroll
            for (int q = 0; q < 5; ++q) {
                float e[7];
#pragma unroll
                for (int i = 0; i < 7; ++i) {
                    e[i] = (q == 0) ? xa[i]
                         : (q == 1) ? ya[i]
                         : (q == 2) ? xa[i] * xa[i]
                         : (q == 3) ? ya[i] * ya[i]
                         :            xa[i] * ya[i];
                }
                const float w2 = e[0] + e[1];
                const float w4 = w2 + (e[2] + e[3]);
                const float w7 = w4 + ((e[4] + e[5]) + e[6]);
                V2[q] = w2 + r2[q];
                V4[q] = w4 + (r4[0][q] + r4[1][q] + r4[2][q]);
                V7[q] = w7 + ((r7[0][q] + r7[1][q]) + (r7[2][q] + r7[3][q])
                              + (r7[4][q] + r7[5][q]));
                r2[q] = w2;
                r4[2][q] = r4[1][q]; r4[1][q] = r4[0][q]; r4[0][q] = w4;
                r7[5][q] = r7[4][q]; r7[4][q] = r7[3][q]; r7[3][q] = r7[2][q];
                r7[2][q] = r7[1][q]; r7[1][q] = r7[0][q]; r7[0][q] = w7;
            }

            // k=1 (closed form), output row i=u, col j=c
            if (u >= R0 && u < R1 && u < 384) {
                const float s = fmaf(2.f, xv * yv, C1) *
                                __builtin_amdgcn_rcpf(fmaf(xv, xv, fmaf(yv, yv, C1)));
                ss1 = fmaf(s, m1, ss1);
            }
            // k=2, i=u
            if (u >= R0 && u < R1 && u < 385) {
                ss2 = fmaf(ssim_u(V2, 4.f, C1_2, C2_2), m2, ss2);
            }
            // k=4, i=u-1
            {
                const int i = u - 1;
                if (i >= R0 && i < R1 && i < 385) {
                    ss4 = fmaf(ssim_u(V4, 16.f, C1_4, C2_4), m4, ss4);
                }
            }
            // k=7, i=u-3, plus L1 (|Sx-Sy|, 1/49 applied in reduce)
            {
                const int i = u - 3;
                if (i >= R0 && i < R1 && i < 384) {
                    ss7 = fmaf(ssim_u(V7, 49.f, C1_7, C2_7), m7, ss7);
                    l1  = fmaf(fabsf(V7[0] - V7[1]), m7, l1);
                }
            }
        }
    }

    // wave reduce -> block reduce -> one float store per block per quantity
#pragma unroll
    for (int d = 32; d > 0; d >>= 1) {
        ss1 += __shfl_down(ss1, d, 64);
        ss2 += __shfl_down(ss2, d, 64);
        ss4 += __shfl_down(ss4, d, 64);
        ss7 += __shfl_down(ss7, d, 64);
        l1  += __shfl_down(l1,  d, 64);
    }
    __shared__ float sred[4][5];
    if (lane == 0) {
        sred[wv][0] = ss1; sred[wv][1] = ss2; sred[wv][2] = ss4;
        sred[wv][3] = ss7; sred[wv][4] = l1;
    }
    __syncthreads();
    if (threadIdx.x == 0) {
        const int bid = ((int)blockIdx.z * 2 + (int)blockIdx.y) * NTILES + (int)blockIdx.x;
#pragma unroll
        for (int q = 0; q < 5; ++q)
            part[bid * 5 + q] = sred[0][q] + sred[1][q] + sred[2][q] + sred[3][q];
    }
}

__global__ __launch_bounds__(256) void reduce_final(
    const float* __restrict__ part, float* __restrict__ out)
{
    const int lane = threadIdx.x & 63;
    const int wv   = threadIdx.x >> 6;
    double d[5] = {0, 0, 0, 0, 0};
    for (int i = threadIdx.x; i < NBLK; i += 256) {
#pragma unroll
        for (int q = 0; q < 5; ++q) d[q] += (double)part[i * 5 + q];
    }
#pragma unroll
    for (int s = 32; s > 0; s >>= 1) {
#pragma unroll
        for (int q = 0; q < 5; ++q) d[q] += __shfl_down(d[q], s, 64);
    }
    __shared__ double sd[4][5];
    if (lane == 0) {
#pragma unroll
        for (int q = 0; q < 5; ++q) sd[wv][q] = d[q];
    }
    __syncthreads();
    if (threadIdx.x == 0) {
        double a[5];
#pragma unroll
        for (int q = 0; q < 5; ++q)
            a[q] = sd[0][q] + sd[1][q] + sd[2][q] + sd[3][q];
        const double n384 = (double)NB * 384.0 * 384.0;
        const double n385 = (double)NB * 385.0 * 385.0;
        const double m  = (a[0] / n384) * (a[1] / n385) * (a[2] / n385) * (a[3] / n384);
        const double l1 = a[4] / 49.0 / n384;
        out[0] = (float)(0.84 * (1.0 - m) + 0.16 * l1);
    }
}

extern "C" void kernel_launch(void* const* d_in, const int* in_sizes, int n_in,
                              void* d_out, int out_size, void* d_ws, size_t ws_size,
                              hipStream_t stream) {
    const float* X  = (const float*)d_in[0];
    const float* Y  = (const float*)d_in[1];
    const float* dr = (const float*)d_in[2];
    float* out  = (float*)d_out;
    float* part = (float*)d_ws;   // NBLK*5 floats = 35.8 KB

    dim3 grid(NTILES, 2, NB);
    msssim_main<<<grid, 256, 0, stream>>>(X, Y, dr, part);
    reduce_final<<<1, 256, 0, stream>>>(part, out);
}

// Round 6
// 290.527 us; speedup vs baseline: 2.1398x; 1.0639x over previous
//
#include <hip/hip_runtime.h>

// Fused MS-SSIM + L1, single pass. B=128, H=W=384 fp32.
// Levels k=1,2,4,7, box conv, zero pad p=k/2 (even k -> 385x385 output).
// Round 6: software-pipelined column-ownership kernel.
//   load(u+2) -> bpermute(u+1) -> compute(u)
// Each lane owns ONE column (c = -3+56*tile+lane). 12 ds_bpermute shifts
// per row are issued one step ahead into alternating A/B register sets so
// their latency is covered by a full step of VALU. Constant trip count
// (BAND=48 -> 54 steps = 9x6 phases, no break) so all ring/slot indices
// are static and fully renamed. Vertical via register rings (validated
// r2-r5); block partials + tiny reduce kernel (validated r4-r5).

#define W 384
#define H 384
#define NB 128
#define BAND 48
#define NTILES 7
#define NBLK (NTILES * 2 * NB)   // grid (7,2,128) = 1792 blocks

__device__ __forceinline__ float bp(int addr, float v) {
    return __int_as_float(__builtin_amdgcn_ds_bpermute(addr, __float_as_int(v)));
}

// S for box window k*k from UNNORMALIZED sums V = {Sx,Sy,Sxx,Syy,Sxy}.
// k2 = k^2, c1k4 = C1*k^4, c2k4 = C2*k^4 (1/k^2 factors cancel).
__device__ __forceinline__ float ssim_u(const float* V, float k2, float c1k4, float c2k4) {
    const float Sx = V[0], Sy = V[1], Sxx = V[2], Syy = V[3], Sxy = V[4];
    const float p  = Sx * Sy;
    float sq = Sx * Sx;
    sq = fmaf(Sy, Sy, sq);
    const float A1 = fmaf(2.f, p, c1k4);
    const float t  = fmaf(k2, Sxy, -p);
    const float A2 = fmaf(2.f, t, c2k4);
    const float B1 = sq + c1k4;
    const float sw = Sxx + Syy;
    const float B2 = fmaf(k2, sw, -sq) + c2k4;
    return (A1 * A2) * __builtin_amdgcn_rcpf(B1 * B2);
}

__global__ __launch_bounds__(256) void msssim_main(
    const float* __restrict__ X, const float* __restrict__ Y,
    const float* __restrict__ dr, float* __restrict__ part)
{
    const int lane = threadIdx.x & 63;
    const int wv   = threadIdx.x >> 6;          // 0..3
    const int tile = blockIdx.x;                // 0..6
    const int band = blockIdx.y * 4 + wv;       // 0..7
    const int b    = blockIdx.z;

    const int cbase = -3 + 56 * tile;           // window-start col of lane 0
    const int c     = cbase + lane;             // this lane's column
    const int R0    = BAND * band;

    // per-level output-row bounds (wave-uniform):
    // k1,k7 outputs: 384 rows; k2,k4: 385 rows (band 7 takes the extra row)
    const int g1hi  = R0 + 48;                       // k1,k7: [R0, R0+48)
    const int g24hi = (band == 7) ? 385 : R0 + 48;   // k2,k4: [R0, g24hi)

    const float drb = dr[b];
    const float C1 = (0.01f * drb) * (0.01f * drb);
    const float C2 = (0.03f * drb) * (0.03f * drb);
    const float C1_2 = C1 * 16.f,   C2_2 = C2 * 16.f;     // k=2
    const float C1_4 = C1 * 256.f,  C2_4 = C2 * 256.f;    // k=4
    const float C1_7 = C1 * 2401.f, C2_7 = C2 * 2401.f;   // k=7

    // ownership masks (validated rounds 2-5): output col j = c + k/2
    const float m1 = (lane >= 3 && lane <= 58 && c     <= 383) ? 1.f : 0.f;
    const float m2 = (lane >= 2 && lane <= 57 && c + 1 <= 384) ? 1.f : 0.f;
    const float m4 = (lane >= 1 && lane <= 56 && c + 2 <= 384) ? 1.f : 0.f;
    const float m7 = (             lane <= 55 && c + 3 <= 383) ? 1.f : 0.f;

    // own-column load setup (clamped offset + zero mask, row-invariant)
    const float mcol = (c >= 0 && c < W) ? 1.f : 0.f;
    const int   cc   = c < 0 ? 0 : (c > W - 1 ? W - 1 : c);

    // bpermute byte addresses for shifts d=1..6 (hw wraps mod 64; wrapped
    // lanes produce garbage that the ownership masks exclude)
    int ad[6];
#pragma unroll
    for (int d = 1; d <= 6; ++d) ad[d - 1] = ((lane + d) & 63) << 2;

    const float* __restrict__ Xb = X + (size_t)b * (H * W);
    const float* __restrict__ Yb = Y + (size_t)b * (H * W);

    // vertical ring buffers of horizontal window sums (per quantity)
    float r2[5], r4[3][5], r7[6][5];
#pragma unroll
    for (int q = 0; q < 5; ++q) {
        r2[q] = 0.f;
        r4[0][q] = r4[1][q] = r4[2][q] = 0.f;
#pragma unroll
        for (int a = 0; a < 6; ++a) r7[a][q] = 0.f;
    }

    float ss1 = 0.f, ss2 = 0.f, ss4 = 0.f, ss7 = 0.f, l1 = 0.f;

    const int u0 = R0 - 3;        // 54 steps: u in [R0-3, R0+50]

    // 3-slot rotating raw-value prefetch (depth 2)
    float px[3], py[3];
    auto loadv = [&](int u, float& x, float& y) {
        if (u >= 0 && u < H) {               // wave-uniform branch
            x = Xb[(size_t)u * W + cc] * mcol;
            y = Yb[(size_t)u * W + cc] * mcol;
        } else { x = 0.f; y = 0.f; }
    };

    // A/B shifted-value sets: set filled at step t-1, consumed at step t
    float Ax[7], Ay[7], Bx[7], By[7];
    auto do_bperm = [&](float xv, float yv, float* sx, float* sy) {
        sx[0] = xv; sy[0] = yv;
#pragma unroll
        for (int d = 1; d <= 6; ++d) {
            sx[d] = bp(ad[d - 1], xv);
            sy[d] = bp(ad[d - 1], yv);
        }
    };

    // prologue: slot0=row u0, slot1=row u0+1; A = shifts of row u0
    loadv(u0,     px[0], py[0]);
    loadv(u0 + 1, px[1], py[1]);
    do_bperm(px[0], py[0], Ax, Ay);

    for (int s = 0; s < 54; s += 6) {
#pragma unroll
        for (int ph = 0; ph < 6; ++ph) {
            const int u = u0 + s + ph;       // compute row (t = s+ph, s%6==0)

            // stage 1: load row u+2 into slot (t+2)%3 = (ph+2)%3
            loadv(u + 2, px[(ph + 2) % 3], py[(ph + 2) % 3]);

            // stage 2: bpermute row u+1 (slot (ph+1)%3) into the idle set
            // stage 3: compute row u from the set filled last step
            const bool evenT = ((ph & 1) == 0);
            float* nx = evenT ? Bx : Ax;
            float* ny = evenT ? By : Ay;
            const float* xa = evenT ? Ax : Bx;
            const float* ya = evenT ? Ay : By;
            do_bperm(px[(ph + 1) % 3], py[(ph + 1) % 3], nx, ny);

            float V2[5], V4[5], V7[5];
#pragma unroll
            for (int q = 0; q < 5; ++q) {
                float e[7];
#pragma unroll
                for (int i = 0; i < 7; ++i) {
                    e[i] = (q == 0) ? xa[i]
                         : (q == 1) ? ya[i]
                         : (q == 2) ? xa[i] * xa[i]
                         : (q == 3) ? ya[i] * ya[i]
                         :            xa[i] * ya[i];
                }
                const float w2 = e[0] + e[1];
                const float w4 = w2 + (e[2] + e[3]);
                const float w7 = w4 + ((e[4] + e[5]) + e[6]);
                V2[q] = w2 + r2[q];
                V4[q] = w4 + (r4[0][q] + r4[1][q] + r4[2][q]);
                V7[q] = w7 + ((r7[0][q] + r7[1][q]) + (r7[2][q] + r7[3][q])
                              + (r7[4][q] + r7[5][q]));
                r2[q] = w2;
                r4[2][q] = r4[1][q]; r4[1][q] = r4[0][q]; r4[0][q] = w4;
                r7[5][q] = r7[4][q]; r7[4][q] = r7[3][q]; r7[3][q] = r7[2][q];
                r7[2][q] = r7[1][q]; r7[1][q] = r7[0][q]; r7[0][q] = w7;
            }

            // k=1 (closed form), output row i=u, col j=c
            if (u >= R0 && u < g1hi) {   // g1hi = R0+48 <= 384 always
                const float xv = xa[0], yv = ya[0];
                const float s1 = fmaf(2.f, xv * yv, C1) *
                                 __builtin_amdgcn_rcpf(fmaf(xv, xv, fmaf(yv, yv, C1)));
                ss1 = fmaf(s1, m1, ss1);
            }
            // k=2, i=u
            if (u >= R0 && u < g24hi) {
                ss2 = fmaf(ssim_u(V2, 4.f, C1_2, C2_2), m2, ss2);
            }
            // k=4, i=u-1
            {
                const int i = u - 1;
                if (i >= R0 && i < g24hi) {
                    ss4 = fmaf(ssim_u(V4, 16.f, C1_4, C2_4), m4, ss4);
                }
            }
            // k=7, i=u-3, plus L1 (|Sx-Sy|, 1/49 applied in reduce)
            {
                const int i = u - 3;
                if (i >= R0 && i < g1hi) {
                    ss7 = fmaf(ssim_u(V7, 49.f, C1_7, C2_7), m7, ss7);
                    l1  = fmaf(fabsf(V7[0] - V7[1]), m7, l1);
                }
            }
        }
    }

    // wave reduce -> block reduce -> one float store per block per quantity
#pragma unroll
    for (int d = 32; d > 0; d >>= 1) {
        ss1 += __shfl_down(ss1, d, 64);
        ss2 += __shfl_down(ss2, d, 64);
        ss4 += __shfl_down(ss4, d, 64);
        ss7 += __shfl_down(ss7, d, 64);
        l1  += __shfl_down(l1,  d, 64);
    }
    __shared__ float sred[4][5];
    if (lane == 0) {
        sred[wv][0] = ss1; sred[wv][1] = ss2; sred[wv][2] = ss4;
        sred[wv][3] = ss7; sred[wv][4] = l1;
    }
    __syncthreads();
    if (threadIdx.x == 0) {
        const int bid = ((int)blockIdx.z * 2 + (int)blockIdx.y) * NTILES + (int)blockIdx.x;
#pragma unroll
        for (int q = 0; q < 5; ++q)
            part[bid * 5 + q] = sred[0][q] + sred[1][q] + sred[2][q] + sred[3][q];
    }
}

__global__ __launch_bounds__(256) void reduce_final(
    const float* __restrict__ part, float* __restrict__ out)
{
    const int lane = threadIdx.x & 63;
    const int wv   = threadIdx.x >> 6;
    double d[5] = {0, 0, 0, 0, 0};
    for (int i = threadIdx.x; i < NBLK; i += 256) {
#pragma unroll
        for (int q = 0; q < 5; ++q) d[q] += (double)part[i * 5 + q];
    }
#pragma unroll
    for (int s = 32; s > 0; s >>= 1) {
#pragma unroll
        for (int q = 0; q < 5; ++q) d[q] += __shfl_down(d[q], s, 64);
    }
    __shared__ double sd[4][5];
    if (lane == 0) {
#pragma unroll
        for (int q = 0; q < 5; ++q) sd[wv][q] = d[q];
    }
    __syncthreads();
    if (threadIdx.x == 0) {
        double a[5];
#pragma unroll
        for (int q = 0; q < 5; ++q)
            a[q] = sd[0][q] + sd[1][q] + sd[2][q] + sd[3][q];
        const double n384 = (double)NB * 384.0 * 384.0;
        const double n385 = (double)NB * 385.0 * 385.0;
        const double m  = (a[0] / n384) * (a[1] / n385) * (a[2] / n385) * (a[3] / n384);
        const double l1 = a[4] / 49.0 / n384;
        out[0] = (float)(0.84 * (1.0 - m) + 0.16 * l1);
    }
}

extern "C" void kernel_launch(void* const* d_in, const int* in_sizes, int n_in,
                              void* d_out, int out_size, void* d_ws, size_t ws_size,
                              hipStream_t stream) {
    const float* X  = (const float*)d_in[0];
    const float* Y  = (const float*)d_in[1];
    const float* dr = (const float*)d_in[2];
    float* out  = (float*)d_out;
    float* part = (float*)d_ws;   // NBLK*5 floats = 35.8 KB

    dim3 grid(NTILES, 2, NB);
    msssim_main<<<grid, 256, 0, stream>>>(X, Y, dr, part);
    reduce_final<<<1, 256, 0, stream>>>(part, out);
}

// Round 7
// 230.002 us; speedup vs baseline: 2.7029x; 1.2632x over previous
//
#include <hip/hip_runtime.h>

// Fused MS-SSIM + L1, single pass. B=128, H=W=384 fp32.
// Levels k=1,2,4,7, box conv, zero pad p=k/2 (even k -> 385x385 output).
// Round 7: fix the vmcnt anchor. Loads go RAW into a 6-slot register ring
// (no mask-mul at the load site, so the compiler's s_waitcnt lands at first
// true use). Pipeline:  load(u+3) -> bpermute(u+1, masked input) -> compute(u)
// giving a 2-step load->use gap that covers HBM latency. Boundary mask mcol
// is applied to the bpermute INPUT (per-source-column masking, semantics
// identical to the pre-masked ring validated in r5/r6). Everything else
// (ownership masks, vertical rings, A/B bperm sets, block partials) is the
// validated r6 structure.

#define W 384
#define H 384
#define NB 128
#define BAND 48
#define NTILES 7
#define NBLK (NTILES * 2 * NB)   // grid (7,2,128) = 1792 blocks

__device__ __forceinline__ float bp(int addr, float v) {
    return __int_as_float(__builtin_amdgcn_ds_bpermute(addr, __float_as_int(v)));
}

// S for box window k*k from UNNORMALIZED sums V = {Sx,Sy,Sxx,Syy,Sxy}.
// k2 = k^2, c1k4 = C1*k^4, c2k4 = C2*k^4 (1/k^2 factors cancel).
__device__ __forceinline__ float ssim_u(const float* V, float k2, float c1k4, float c2k4) {
    const float Sx = V[0], Sy = V[1], Sxx = V[2], Syy = V[3], Sxy = V[4];
    const float p  = Sx * Sy;
    float sq = Sx * Sx;
    sq = fmaf(Sy, Sy, sq);
    const float A1 = fmaf(2.f, p, c1k4);
    const float t  = fmaf(k2, Sxy, -p);
    const float A2 = fmaf(2.f, t, c2k4);
    const float B1 = sq + c1k4;
    const float sw = Sxx + Syy;
    const float B2 = fmaf(k2, sw, -sq) + c2k4;
    return (A1 * A2) * __builtin_amdgcn_rcpf(B1 * B2);
}

__global__ __launch_bounds__(256) void msssim_main(
    const float* __restrict__ X, const float* __restrict__ Y,
    const float* __restrict__ dr, float* __restrict__ part)
{
    const int lane = threadIdx.x & 63;
    const int wv   = threadIdx.x >> 6;          // 0..3
    const int tile = blockIdx.x;                // 0..6
    const int band = blockIdx.y * 4 + wv;       // 0..7
    const int b    = blockIdx.z;

    const int cbase = -3 + 56 * tile;           // window-start col of lane 0
    const int c     = cbase + lane;             // this lane's column
    const int R0    = BAND * band;

    // per-level output-row bounds (wave-uniform):
    // k1,k7 outputs: 384 rows; k2,k4: 385 rows (band 7 takes the extra row)
    const int g1hi  = R0 + 48;                       // k1,k7: [R0, R0+48)
    const int g24hi = (band == 7) ? 385 : R0 + 48;   // k2,k4: [R0, g24hi)

    const float drb = dr[b];
    const float C1 = (0.01f * drb) * (0.01f * drb);
    const float C2 = (0.03f * drb) * (0.03f * drb);
    const float C1_2 = C1 * 16.f,   C2_2 = C2 * 16.f;     // k=2
    const float C1_4 = C1 * 256.f,  C2_4 = C2 * 256.f;    // k=4
    const float C1_7 = C1 * 2401.f, C2_7 = C2 * 2401.f;   // k=7

    // ownership masks (validated rounds 2-6): output col j = c + k/2
    const float m1 = (lane >= 3 && lane <= 58 && c     <= 383) ? 1.f : 0.f;
    const float m2 = (lane >= 2 && lane <= 57 && c + 1 <= 384) ? 1.f : 0.f;
    const float m4 = (lane >= 1 && lane <= 56 && c + 2 <= 384) ? 1.f : 0.f;
    const float m7 = (             lane <= 55 && c + 3 <= 383) ? 1.f : 0.f;

    // own-column load setup (clamped offset + zero mask, row-invariant)
    const float mcol = (c >= 0 && c < W) ? 1.f : 0.f;
    const int   cc   = c < 0 ? 0 : (c > W - 1 ? W - 1 : c);

    // bpermute byte addresses for shifts d=1..6 (hw wraps mod 64; wrapped
    // lanes produce garbage that the ownership masks exclude)
    int ad[6];
#pragma unroll
    for (int d = 1; d <= 6; ++d) ad[d - 1] = ((lane + d) & 63) << 2;

    const float* __restrict__ Xb = X + (size_t)b * (H * W);
    const float* __restrict__ Yb = Y + (size_t)b * (H * W);

    // vertical ring buffers of horizontal window sums (per quantity)
    float r2[5], r4[3][5], r7[6][5];
#pragma unroll
    for (int q = 0; q < 5; ++q) {
        r2[q] = 0.f;
        r4[0][q] = r4[1][q] = r4[2][q] = 0.f;
#pragma unroll
        for (int a = 0; a < 6; ++a) r7[a][q] = 0.f;
    }

    float ss1 = 0.f, ss2 = 0.f, ss4 = 0.f, ss7 = 0.f, l1 = 0.f;

    const int u0 = R0 - 3;        // 54 steps: u in [R0-3, R0+50]

    // 6-slot raw-value ring: slot s holds row r with (r - u0) % 6 == s.
    // RAW loads only (no mask arithmetic) so the vmcnt wait sinks to use.
    float px[6], py[6];
    auto loadv = [&](int u, float& x, float& y) {
        if (u >= 0 && u < H) {               // wave-uniform branch
            x = Xb[(size_t)u * W + cc];
            y = Yb[(size_t)u * W + cc];
        } else { x = 0.f; y = 0.f; }
    };

    // A/B shifted-value sets: set filled at step t-1, consumed at step t.
    // Mask applied to the bpermute INPUT (per-source-column masking).
    float Ax[7], Ay[7], Bx[7], By[7];
    auto do_bperm = [&](float xr, float yr, float* sx, float* sy) {
        const float xv = xr * mcol;
        const float yv = yr * mcol;
        sx[0] = xv; sy[0] = yv;
#pragma unroll
        for (int d = 1; d <= 6; ++d) {
            sx[d] = bp(ad[d - 1], xv);
            sy[d] = bp(ad[d - 1], yv);
        }
    };

    // prologue: preload rows u0, u0+1, u0+2; A = shifts of row u0
    loadv(u0,     px[0], py[0]);
    loadv(u0 + 1, px[1], py[1]);
    loadv(u0 + 2, px[2], py[2]);
    do_bperm(px[0], py[0], Ax, Ay);

    for (int s = 0; s < 54; s += 6) {
#pragma unroll
        for (int ph = 0; ph < 6; ++ph) {
            const int u = u0 + s + ph;       // compute row (t = s+ph)

            // stage 1: load row u+3 into slot (ph+3)%6  (gap 2 to bperm)
            loadv(u + 3, px[(ph + 3) % 6], py[(ph + 3) % 6]);

            // stage 2: bpermute row u+1 (slot (ph+1)%6, loaded 2 steps ago)
            // stage 3: compute row u from the set filled last step
            const bool evenT = ((ph & 1) == 0);
            float* nx = evenT ? Bx : Ax;
            float* ny = evenT ? By : Ay;
            const float* xa = evenT ? Ax : Bx;
            const float* ya = evenT ? Ay : By;
            do_bperm(px[(ph + 1) % 6], py[(ph + 1) % 6], nx, ny);

            float V2[5], V4[5], V7[5];
#pragma unroll
            for (int q = 0; q < 5; ++q) {
                float e[7];
#pragma unroll
                for (int i = 0; i < 7; ++i) {
                    e[i] = (q == 0) ? xa[i]
                         : (q == 1) ? ya[i]
                         : (q == 2) ? xa[i] * xa[i]
                         : (q == 3) ? ya[i] * ya[i]
                         :            xa[i] * ya[i];
                }
                const float w2 = e[0] + e[1];
                const float w4 = w2 + (e[2] + e[3]);
                const float w7 = w4 + ((e[4] + e[5]) + e[6]);
                V2[q] = w2 + r2[q];
                V4[q] = w4 + (r4[0][q] + r4[1][q] + r4[2][q]);
                V7[q] = w7 + ((r7[0][q] + r7[1][q]) + (r7[2][q] + r7[3][q])
                              + (r7[4][q] + r7[5][q]));
                r2[q] = w2;
                r4[2][q] = r4[1][q]; r4[1][q] = r4[0][q]; r4[0][q] = w4;
                r7[5][q] = r7[4][q]; r7[4][q] = r7[3][q]; r7[3][q] = r7[2][q];
                r7[2][q] = r7[1][q]; r7[1][q] = r7[0][q]; r7[0][q] = w7;
            }

            // k=1 (closed form), output row i=u, col j=c
            if (u >= R0 && u < g1hi) {   // g1hi = R0+48 <= 384 always
                const float xv = xa[0], yv = ya[0];
                const float s1 = fmaf(2.f, xv * yv, C1) *
                                 __builtin_amdgcn_rcpf(fmaf(xv, xv, fmaf(yv, yv, C1)));
                ss1 = fmaf(s1, m1, ss1);
            }
            // k=2, i=u
            if (u >= R0 && u < g24hi) {
                ss2 = fmaf(ssim_u(V2, 4.f, C1_2, C2_2), m2, ss2);
            }
            // k=4, i=u-1
            {
                const int i = u - 1;
                if (i >= R0 && i < g24hi) {
                    ss4 = fmaf(ssim_u(V4, 16.f, C1_4, C2_4), m4, ss4);
                }
            }
            // k=7, i=u-3, plus L1 (|Sx-Sy|, 1/49 applied in reduce)
            {
                const int i = u - 3;
                if (i >= R0 && i < g1hi) {
                    ss7 = fmaf(ssim_u(V7, 49.f, C1_7, C2_7), m7, ss7);
                    l1  = fmaf(fabsf(V7[0] - V7[1]), m7, l1);
                }
            }
        }
    }

    // wave reduce -> block reduce -> one float store per block per quantity
#pragma unroll
    for (int d = 32; d > 0; d >>= 1) {
        ss1 += __shfl_down(ss1, d, 64);
        ss2 += __shfl_down(ss2, d, 64);
        ss4 += __shfl_down(ss4, d, 64);
        ss7 += __shfl_down(ss7, d, 64);
        l1  += __shfl_down(l1,  d, 64);
    }
    __shared__ float sred[4][5];
    if (lane == 0) {
        sred[wv][0] = ss1; sred[wv][1] = ss2; sred[wv][2] = ss4;
        sred[wv][3] = ss7; sred[wv][4] = l1;
    }
    __syncthreads();
    if (threadIdx.x == 0) {
        const int bid = ((int)blockIdx.z * 2 + (int)blockIdx.y) * NTILES + (int)blockIdx.x;
#pragma unroll
        for (int q = 0; q < 5; ++q)
            part[bid * 5 + q] = sred[0][q] + sred[1][q] + sred[2][q] + sred[3][q];
    }
}

__global__ __launch_bounds__(256) void reduce_final(
    const float* __restrict__ part, float* __restrict__ out)
{
    const int lane = threadIdx.x & 63;
    const int wv   = threadIdx.x >> 6;
    double d[5] = {0, 0, 0, 0, 0};
    for (int i = threadIdx.x; i < NBLK; i += 256) {
#pragma unroll
        for (int q = 0; q < 5; ++q) d[q] += (double)part[i * 5 + q];
    }
#pragma unroll
    for (int s = 32; s > 0; s >>= 1) {
#pragma unroll
        for (int q = 0; q < 5; ++q) d[q] += __shfl_down(d[q], s, 64);
    }
    __shared__ double sd[4][5];
    if (lane == 0) {
#pragma unroll
        for (int q = 0; q < 5; ++q) sd[wv][q] = d[q];
    }
    __syncthreads();
    if (threadIdx.x == 0) {
        double a[5];
#pragma unroll
        for (int q = 0; q < 5; ++q)
            a[q] = sd[0][q] + sd[1][q] + sd[2][q] + sd[3][q];
        const double n384 = (double)NB * 384.0 * 384.0;
        const double n385 = (double)NB * 385.0 * 385.0;
        const double m  = (a[0] / n384) * (a[1] / n385) * (a[2] / n385) * (a[3] / n384);
        const double l1 = a[4] / 49.0 / n384;
        out[0] = (float)(0.84 * (1.0 - m) + 0.16 * l1);
    }
}

extern "C" void kernel_launch(void* const* d_in, const int* in_sizes, int n_in,
                              void* d_out, int out_size, void* d_ws, size_t ws_size,
                              hipStream_t stream) {
    const float* X  = (const float*)d_in[0];
    const float* Y  = (const float*)d_in[1];
    const float* dr = (const float*)d_in[2];
    float* out  = (float*)d_out;
    float* part = (float*)d_ws;   // NBLK*5 floats = 35.8 KB

    dim3 grid(NTILES, 2, NB);
    msssim_main<<<grid, 256, 0, stream>>>(X, Y, dr, part);
    reduce_final<<<1, 256, 0, stream>>>(part, out);
}